// Round 2
// baseline (495.846 us; speedup 1.0000x reference)
//
#include <hip/hip_runtime.h>
#include <stdint.h>

#define B_  4
#define S_  2048
#define DM_ 1024
#define NH_ 16
#define HD_ 64

typedef unsigned short ushort_t;
typedef __bf16 bf16x8 __attribute__((ext_vector_type(8)));
typedef float  floatx4 __attribute__((ext_vector_type(4)));

__device__ __forceinline__ float bf2f(ushort_t u) {
    union { unsigned int i; float f; } v; v.i = ((unsigned int)u) << 16; return v.f;
}
__device__ __forceinline__ ushort_t f2bf(float f) {
    union { float f; unsigned int i; } v; v.f = f;
    unsigned int x = v.i;
    return (ushort_t)((x + 0x7fffu + ((x >> 16) & 1u)) >> 16);
}

// ---------------------------------------------------------------------------
// f32 -> bf16 conversion (vectorized, n divisible by 1024)
// ---------------------------------------------------------------------------
__global__ __launch_bounds__(256) void cvt_kernel(
    const float* __restrict__ src, ushort_t* __restrict__ dst)
{
    const int i = blockIdx.x * 256 + threadIdx.x;
    float4 v = ((const float4*)src)[i];
    ushort_t o0 = f2bf(v.x), o1 = f2bf(v.y), o2 = f2bf(v.z), o3 = f2bf(v.w);
    ushort4 o; o.x = o0; o.y = o1; o.z = o2; o.w = o3;
    ((ushort4*)dst)[i] = o;
}

// ---------------------------------------------------------------------------
// GEMM: C = A @ B^T.  A: (M,K) row-major bf16.  Bw: (N,K) row-major bf16.
// mode 0: bf16 out, C[m,n] -> out[((b*NH+h)*S + s)*64 + d]  (B,H,S,64)
// mode 1: f32  out, C[m,n] -> out[m*N + n]                  (row-major)
// m97 structure: 128x128 tile, BK=32, global_load_lds width 16, 4 waves.
// ---------------------------------------------------------------------------
__global__ __launch_bounds__(256) void gemm_bt_kernel(
    const ushort_t* __restrict__ A, const ushort_t* __restrict__ Bw,
    void* __restrict__ Cv, int M, int N, int K, int mode)
{
    __shared__ ushort_t As[128 * 32];
    __shared__ ushort_t Bs[128 * 32];
    const int tid  = threadIdx.x;
    const int mbase = blockIdx.x * 128;
    const int nbase = blockIdx.y * 128;
    const int wave = tid >> 6, lane = tid & 63;
    const int l15 = lane & 15, quad = lane >> 4;
    const int wm = (wave & 1) * 64, wn = (wave >> 1) * 64;

    floatx4 acc[4][4] = {};

    const int e0   = tid * 8;        // element index of this thread's 16B chunk
    const int row0 = e0 >> 5;        // 32 elems per row
    const int col0 = e0 & 31;

    for (int kt = 0; kt < K; kt += 32) {
        __syncthreads();
#pragma unroll
        for (int r = 0; r < 2; ++r) {
            const int e   = e0 + r * 2048;
            const int row = row0 + r * 64;
            const ushort_t* ga = A  + (size_t)(mbase + row) * K + kt + col0;
            const ushort_t* gb = Bw + (size_t)(nbase + row) * K + kt + col0;
            __builtin_amdgcn_global_load_lds(
                (const __attribute__((address_space(1))) unsigned int*)ga,
                (__attribute__((address_space(3))) unsigned int*)(As + e), 16, 0, 0);
            __builtin_amdgcn_global_load_lds(
                (const __attribute__((address_space(1))) unsigned int*)gb,
                (__attribute__((address_space(3))) unsigned int*)(Bs + e), 16, 0, 0);
        }
        __builtin_amdgcn_s_waitcnt(0);
        __syncthreads();

        bf16x8 af[4], bfr[4];
#pragma unroll
        for (int t = 0; t < 4; ++t) {
            af[t]  = *(const bf16x8*)(As + (wm + t * 16 + l15) * 32 + quad * 8);
            bfr[t] = *(const bf16x8*)(Bs + (wn + t * 16 + l15) * 32 + quad * 8);
        }
#pragma unroll
        for (int mt = 0; mt < 4; ++mt)
#pragma unroll
            for (int nt = 0; nt < 4; ++nt)
                acc[mt][nt] = __builtin_amdgcn_mfma_f32_16x16x32_bf16(
                    af[mt], bfr[nt], acc[mt][nt], 0, 0, 0);
    }

    // epilogue: C/D layout col=lane&15, row=quad*4+reg
#pragma unroll
    for (int mt = 0; mt < 4; ++mt) {
#pragma unroll
        for (int nt = 0; nt < 4; ++nt) {
            const int col = nbase + wn + nt * 16 + l15;
#pragma unroll
            for (int r = 0; r < 4; ++r) {
                const int m = mbase + wm + mt * 16 + quad * 4 + r;
                if (mode == 0) {
                    const int b = m >> 11, s = m & 2047;
                    const int h = col >> 6, d = col & 63;
                    ((ushort_t*)Cv)[(((size_t)(b * NH_ + h)) * S_ + s) * HD_ + d] =
                        f2bf(acc[mt][nt][r]);
                } else {
                    ((float*)Cv)[(size_t)m * N + col] = acc[mt][nt][r];
                }
            }
        }
    }
}

// ---------------------------------------------------------------------------
// RoPE on Q and K in (B,H,S,64) bf16 layout. cos/sin are f32 (S,32).
// ---------------------------------------------------------------------------
__global__ __launch_bounds__(256) void rope_kernel(
    ushort_t* __restrict__ q, ushort_t* __restrict__ k,
    const float* __restrict__ cf, const float* __restrict__ sf)
{
    const int idx = blockIdx.x * 256 + threadIdx.x;   // pair index
    const int j = idx & 31;
    const int s = (idx >> 5) & (S_ - 1);
    const float c  = cf[s * 32 + j];
    const float sn = sf[s * 32 + j];
    const size_t base = (size_t)idx * 2;
    float qe = bf2f(q[base]), qo = bf2f(q[base + 1]);
    q[base]     = f2bf(qe * c - qo * sn);
    q[base + 1] = f2bf(qe * sn + qo * c);
    float ke = bf2f(k[base]), ko = bf2f(k[base + 1]);
    k[base]     = f2bf(ke * c - ko * sn);
    k[base + 1] = f2bf(ke * sn + ko * c);
}

// ---------------------------------------------------------------------------
// Causal flash attention. Block = (64 Q rows, one bh). 4 waves x 16 Q rows.
// Q,K,V bf16 in (B,H,S,64). Output bf16 in (B,S,H*64).
// ---------------------------------------------------------------------------
__global__ __launch_bounds__(256) void attn_kernel(
    const ushort_t* __restrict__ Qg, const ushort_t* __restrict__ Kg,
    const ushort_t* __restrict__ Vg, ushort_t* __restrict__ Og)
{
    __shared__ ushort_t Ks[64 * 72];       // [key][dim], pad 72 for alignment
    __shared__ ushort_t Vt[64 * 72];       // [dim][key ^ swizzle]
    __shared__ ushort_t Ps[4][16 * 72];    // per-wave P tile [qrow][key]

    const int qt  = (gridDim.x - 1) - blockIdx.x;   // longest blocks first
    const int bh  = blockIdx.y;
    const int tid = threadIdx.x;
    const int wave = tid >> 6, lane = tid & 63;
    const int l15 = lane & 15, quad = lane >> 4;
    const float scale = 0.125f;   // 1/sqrt(64)

    const size_t bh_off = (size_t)bh * S_ * HD_;
    const int qbase = qt * 64;

    // Q fragments (A-operand: m = lane&15, k = quad*8+j), kept in regs
    bf16x8 qf[2];
    {
        const int qrow = qbase + wave * 16 + l15;
#pragma unroll
        for (int kk = 0; kk < 2; ++kk)
            qf[kk] = *(const bf16x8*)(Qg + bh_off + (size_t)qrow * HD_ + kk * 32 + quad * 8);
    }

    float m_run[4], l_run[4];
    floatx4 o_acc[4];
#pragma unroll
    for (int r = 0; r < 4; ++r) { m_run[r] = -1e30f; l_run[r] = 0.f; }
#pragma unroll
    for (int nt = 0; nt < 4; ++nt) o_acc[nt] = (floatx4){0.f, 0.f, 0.f, 0.f};

    const int trow = tid >> 3;         // 0..31
    const int tcol = (tid & 7) * 8;    // 0..56

    for (int kt = 0; kt <= qt; ++kt) {
        const int kbase = kt * 64;
        __syncthreads();
        // ---- stage K (natural) and V (transposed+swizzled) ----
#pragma unroll
        for (int r = 0; r < 2; ++r) {
            const int row = trow + r * 32;   // key index in tile
            bf16x8 kv = *(const bf16x8*)(Kg + bh_off + (size_t)(kbase + row) * HD_ + tcol);
            *(bf16x8*)(Ks + row * 72 + tcol) = kv;
            union { bf16x8 v; ushort_t u[8]; } vv;
            vv.v = *(const bf16x8*)(Vg + bh_off + (size_t)(kbase + row) * HD_ + tcol);
#pragma unroll
            for (int i = 0; i < 8; ++i) {
                const int d = tcol + i;
                Vt[d * 72 + (row ^ (((d >> 3) & 7) << 3))] = vv.u[i];
            }
        }
        __syncthreads();

        // ---- S = Q K^T (C layout: col=key=lane&15, row=quad*4+r) ----
        floatx4 sf4[4];
#pragma unroll
        for (int nt = 0; nt < 4; ++nt) {
            floatx4 a = {0.f, 0.f, 0.f, 0.f};
#pragma unroll
            for (int kk = 0; kk < 2; ++kk) {
                bf16x8 kf = *(const bf16x8*)(Ks + (nt * 16 + l15) * 72 + kk * 32 + quad * 8);
                a = __builtin_amdgcn_mfma_f32_16x16x32_bf16(qf[kk], kf, a, 0, 0, 0);
            }
            sf4[nt] = a;
        }
        // ---- scale + causal mask ----
        const int qc = qbase + wave * 16 + quad * 4;
#pragma unroll
        for (int nt = 0; nt < 4; ++nt) {
            const int kidx = kbase + nt * 16 + l15;
#pragma unroll
            for (int r = 0; r < 4; ++r) {
                const float sv = sf4[nt][r] * scale;
                sf4[nt][r] = (kidx <= qc + r) ? sv : -1e9f;
            }
        }
        // ---- online softmax (row = quad*4+r; reduce across 16 lanes of quad) ----
        float alpha[4];
#pragma unroll
        for (int r = 0; r < 4; ++r) {
            float mx = fmaxf(fmaxf(sf4[0][r], sf4[1][r]), fmaxf(sf4[2][r], sf4[3][r]));
#pragma unroll
            for (int off = 1; off < 16; off <<= 1)
                mx = fmaxf(mx, __shfl_xor(mx, off, 64));
            const float mnew = fmaxf(m_run[r], mx);
            alpha[r] = __expf(m_run[r] - mnew);
            m_run[r] = mnew;
        }
        float pv[4][4];
#pragma unroll
        for (int r = 0; r < 4; ++r) {
            float sum = 0.f;
#pragma unroll
            for (int nt = 0; nt < 4; ++nt) {
                const float p = __expf(sf4[nt][r] - m_run[r]);
                pv[nt][r] = p; sum += p;
            }
#pragma unroll
            for (int off = 1; off < 16; off <<= 1)
                sum += __shfl_xor(sum, off, 64);
            l_run[r] = l_run[r] * alpha[r] + sum;
        }
#pragma unroll
        for (int nt = 0; nt < 4; ++nt)
#pragma unroll
            for (int r = 0; r < 4; ++r)
                o_acc[nt][r] *= alpha[r];

        // ---- P: C-layout -> LDS -> A-layout (wave-private tile) ----
#pragma unroll
        for (int nt = 0; nt < 4; ++nt)
#pragma unroll
            for (int r = 0; r < 4; ++r)
                Ps[wave][(quad * 4 + r) * 72 + nt * 16 + l15] = f2bf(pv[nt][r]);
        __syncthreads();
        bf16x8 pf[2];
#pragma unroll
        for (int kk = 0; kk < 2; ++kk)
            pf[kk] = *(const bf16x8*)(&Ps[wave][l15 * 72 + kk * 32 + quad * 8]);

        // ---- O += P V ----
#pragma unroll
        for (int nt = 0; nt < 4; ++nt) {
            const int d = nt * 16 + l15;
#pragma unroll
            for (int kk = 0; kk < 2; ++kk) {
                const int k0 = kk * 32 + quad * 8;
                bf16x8 vf = *(const bf16x8*)(Vt + d * 72 + (k0 ^ (((d >> 3) & 7) << 3)));
                o_acc[nt] = __builtin_amdgcn_mfma_f32_16x16x32_bf16(pf[kk], vf, o_acc[nt], 0, 0, 0);
            }
        }
    }

    // ---- epilogue: normalize, write bf16 (B,S,H*64) ----
    const int b = bh >> 4, h = bh & 15;
#pragma unroll
    for (int nt = 0; nt < 4; ++nt) {
        const int d = nt * 16 + l15;
#pragma unroll
        for (int r = 0; r < 4; ++r) {
            const int qi = qbase + wave * 16 + quad * 4 + r;
            const float v = o_acc[nt][r] / l_run[r];
            Og[((size_t)(b * S_ + qi)) * DM_ + h * HD_ + d] = f2bf(v);
        }
    }
}

// ---------------------------------------------------------------------------
extern "C" void kernel_launch(void* const* d_in, const int* in_sizes, int n_in,
                              void* d_out, int out_size, void* d_ws, size_t ws_size,
                              hipStream_t stream)
{
    const float* x  = (const float*)d_in[0];
    const float* cf = (const float*)d_in[1];
    const float* sf = (const float*)d_in[2];
    // d_in[3] = causal_mask: computed analytically, never read
    const float* wq = (const float*)d_in[4];
    const float* wk = (const float*)d_in[5];
    const float* wv = (const float*)d_in[6];
    const float* wo = (const float*)d_in[7];
    float* out = (float*)d_out;

    const size_t NELEM = (size_t)B_ * S_ * DM_;   // 8388608
    const size_t WELEM = (size_t)DM_ * DM_;       // 1048576
    ushort_t* xb  = (ushort_t*)d_ws;
    ushort_t* qb  = xb + NELEM;
    ushort_t* kb  = qb + NELEM;
    ushort_t* vb  = kb + NELEM;
    ushort_t* ao  = vb + NELEM;
    ushort_t* wqb = ao + NELEM;
    ushort_t* wkb = wqb + WELEM;
    ushort_t* wvb = wkb + WELEM;
    ushort_t* wob = wvb + WELEM;

    // f32 -> bf16 conversions
    cvt_kernel<<<dim3(NELEM / 1024), 256, 0, stream>>>(x,  xb);
    cvt_kernel<<<dim3(WELEM / 1024), 256, 0, stream>>>(wq, wqb);
    cvt_kernel<<<dim3(WELEM / 1024), 256, 0, stream>>>(wk, wkb);
    cvt_kernel<<<dim3(WELEM / 1024), 256, 0, stream>>>(wv, wvb);
    cvt_kernel<<<dim3(WELEM / 1024), 256, 0, stream>>>(wo, wob);

    const int M = B_ * S_;
    dim3 ggrid(M / 128, DM_ / 128);
    gemm_bt_kernel<<<ggrid, 256, 0, stream>>>(xb, wqb, qb, M, DM_, DM_, 0);
    gemm_bt_kernel<<<ggrid, 256, 0, stream>>>(xb, wkb, kb, M, DM_, DM_, 0);
    gemm_bt_kernel<<<ggrid, 256, 0, stream>>>(xb, wvb, vb, M, DM_, DM_, 0);
    rope_kernel<<<dim3((B_ * NH_ * S_ * 32) / 256), 256, 0, stream>>>(qb, kb, cf, sf);
    attn_kernel<<<dim3(S_ / 64, B_ * NH_), 256, 0, stream>>>(qb, kb, vb, ao);
    gemm_bt_kernel<<<ggrid, 256, 0, stream>>>(ao, wob, out, M, DM_, DM_, 1);
}

// Round 3
// 461.883 us; speedup vs baseline: 1.0735x; 1.0735x over previous
//
#include <hip/hip_runtime.h>
#include <stdint.h>

#define B_  4
#define S_  2048
#define DM_ 1024
#define NH_ 16
#define HD_ 64

typedef unsigned short ushort_t;
typedef __bf16 bf16x8 __attribute__((ext_vector_type(8)));
typedef float  floatx4 __attribute__((ext_vector_type(4)));

__device__ __forceinline__ float bf2f(ushort_t u) {
    union { unsigned int i; float f; } v; v.i = ((unsigned int)u) << 16; return v.f;
}
__device__ __forceinline__ ushort_t f2bf(float f) {
    union { float f; unsigned int i; } v; v.f = f;
    unsigned int x = v.i;
    return (ushort_t)((x + 0x7fffu + ((x >> 16) & 1u)) >> 16);
}
// pack two f32 -> two bf16 (truncate) in one v_perm_b32
__device__ __forceinline__ unsigned int pack_bf16_trunc(float lo, float hi) {
    union { float f; unsigned int u; } a, b;
    a.f = lo; b.f = hi;
    return __builtin_amdgcn_perm(b.u, a.u, 0x07060302u);
}
__device__ __forceinline__ floatx4 vmax4(floatx4 a, floatx4 b) {
    floatx4 r;
#pragma unroll
    for (int i = 0; i < 4; ++i) r[i] = fmaxf(a[i], b[i]);
    return r;
}

// ---------------------------------------------------------------------------
// f32 -> bf16 conversion (vectorized, n divisible by 1024)
// ---------------------------------------------------------------------------
__global__ __launch_bounds__(256) void cvt_kernel(
    const float* __restrict__ src, ushort_t* __restrict__ dst)
{
    const int i = blockIdx.x * 256 + threadIdx.x;
    float4 v = ((const float4*)src)[i];
    ushort4 o; o.x = f2bf(v.x); o.y = f2bf(v.y); o.z = f2bf(v.z); o.w = f2bf(v.w);
    ((ushort4*)dst)[i] = o;
}

// ---------------------------------------------------------------------------
// GEMM: C = A @ B^T.  (unchanged m97 structure)
// mode 0: bf16 out -> (B,H,S,64) head-major; mode 1: f32 out row-major
// ---------------------------------------------------------------------------
__global__ __launch_bounds__(256) void gemm_bt_kernel(
    const ushort_t* __restrict__ A, const ushort_t* __restrict__ Bw,
    void* __restrict__ Cv, int M, int N, int K, int mode)
{
    __shared__ ushort_t As[128 * 32];
    __shared__ ushort_t Bs[128 * 32];
    const int tid  = threadIdx.x;
    const int mbase = blockIdx.x * 128;
    const int nbase = blockIdx.y * 128;
    const int wave = tid >> 6, lane = tid & 63;
    const int l15 = lane & 15, quad = lane >> 4;
    const int wm = (wave & 1) * 64, wn = (wave >> 1) * 64;

    floatx4 acc[4][4] = {};

    const int e0   = tid * 8;
    const int row0 = e0 >> 5;
    const int col0 = e0 & 31;

    for (int kt = 0; kt < K; kt += 32) {
        __syncthreads();
#pragma unroll
        for (int r = 0; r < 2; ++r) {
            const int e   = e0 + r * 2048;
            const int row = row0 + r * 64;
            const ushort_t* ga = A  + (size_t)(mbase + row) * K + kt + col0;
            const ushort_t* gb = Bw + (size_t)(nbase + row) * K + kt + col0;
            __builtin_amdgcn_global_load_lds(
                (const __attribute__((address_space(1))) unsigned int*)ga,
                (__attribute__((address_space(3))) unsigned int*)(As + e), 16, 0, 0);
            __builtin_amdgcn_global_load_lds(
                (const __attribute__((address_space(1))) unsigned int*)gb,
                (__attribute__((address_space(3))) unsigned int*)(Bs + e), 16, 0, 0);
        }
        __builtin_amdgcn_s_waitcnt(0);
        __syncthreads();

        bf16x8 af[4], bfr[4];
#pragma unroll
        for (int t = 0; t < 4; ++t) {
            af[t]  = *(const bf16x8*)(As + (wm + t * 16 + l15) * 32 + quad * 8);
            bfr[t] = *(const bf16x8*)(Bs + (wn + t * 16 + l15) * 32 + quad * 8);
        }
#pragma unroll
        for (int mt = 0; mt < 4; ++mt)
#pragma unroll
            for (int nt = 0; nt < 4; ++nt)
                acc[mt][nt] = __builtin_amdgcn_mfma_f32_16x16x32_bf16(
                    af[mt], bfr[nt], acc[mt][nt], 0, 0, 0);
    }

#pragma unroll
    for (int mt = 0; mt < 4; ++mt) {
#pragma unroll
        for (int nt = 0; nt < 4; ++nt) {
            const int col = nbase + wn + nt * 16 + l15;
#pragma unroll
            for (int r = 0; r < 4; ++r) {
                const int m = mbase + wm + mt * 16 + quad * 4 + r;
                if (mode == 0) {
                    const int b = m >> 11, s = m & 2047;
                    const int h = col >> 6, d = col & 63;
                    ((ushort_t*)Cv)[(((size_t)(b * NH_ + h)) * S_ + s) * HD_ + d] =
                        f2bf(acc[mt][nt][r]);
                } else {
                    ((float*)Cv)[(size_t)m * N + col] = acc[mt][nt][r];
                }
            }
        }
    }
}

// ---------------------------------------------------------------------------
// RoPE on Q and K in (B,H,S,64) bf16 layout. cos/sin f32 (S,32).
// ---------------------------------------------------------------------------
__global__ __launch_bounds__(256) void rope_kernel(
    ushort_t* __restrict__ q, ushort_t* __restrict__ k,
    const float* __restrict__ cf, const float* __restrict__ sf)
{
    const int idx = blockIdx.x * 256 + threadIdx.x;
    const int j = idx & 31;
    const int s = (idx >> 5) & (S_ - 1);
    const float c  = cf[s * 32 + j];
    const float sn = sf[s * 32 + j];
    const size_t base = (size_t)idx * 2;
    float qe = bf2f(q[base]), qo = bf2f(q[base + 1]);
    q[base]     = f2bf(qe * c - qo * sn);
    q[base + 1] = f2bf(qe * sn + qo * c);
    float ke = bf2f(k[base]), ko = bf2f(k[base + 1]);
    k[base]     = f2bf(ke * c - ko * sn);
    k[base + 1] = f2bf(ke * sn + ko * c);
}

// ---------------------------------------------------------------------------
// Causal flash attention, S^T/O^T formulation.
// Block = 128 Q rows x one bh; 4 waves x 32 q-rows (2 groups of 16).
// S^T = K·Q^T  => C layout: col=q (lane&15), row=key (quad*4+r)
//   -> softmax rows live per-lane: in-lane reduce + 2 shuffles.
// O^T = V^T·P^T, P^T round trip through wave-private LDS (no barrier).
// ---------------------------------------------------------------------------
__global__ __launch_bounds__(256, 4) void attn_kernel(
    const ushort_t* __restrict__ Qg, const ushort_t* __restrict__ Kg,
    const ushort_t* __restrict__ Vg, ushort_t* __restrict__ Og)
{
    __shared__ ushort_t Ks[64 * 72];        // [key][dim]
    __shared__ ushort_t Vt[64 * 72];        // [dim][key ^ swizzle]
    __shared__ ushort_t Pt[4][32 * 72];     // per-wave P^T as [q][key]

    const int qt  = (gridDim.x - 1) - blockIdx.x;   // longest blocks first
    const int bh  = blockIdx.y;
    const int tid = threadIdx.x;
    const int wave = tid >> 6, lane = tid & 63;
    const int l15 = lane & 15, quad = lane >> 4;
    const float scale = 0.125f;

    const size_t bh_off = (size_t)bh * S_ * HD_;
    const int qbase = qt * 128;

    // Q fragments (B-operand: n=q=lane&15, k=d=quad*8+j): [g][kk]
    bf16x8 qf[2][2];
#pragma unroll
    for (int g = 0; g < 2; ++g) {
        const int qrow = qbase + wave * 32 + g * 16 + l15;
#pragma unroll
        for (int kk = 0; kk < 2; ++kk)
            qf[g][kk] = *(const bf16x8*)(Qg + bh_off + (size_t)qrow * HD_ + kk * 32 + quad * 8);
    }

    float m_run[2] = { -1e30f, -1e30f };
    float l_run[2] = { 0.f, 0.f };
    floatx4 o_acc[2][4] = {};   // [g][d-tile], col=q, row=d=quad*4+r

    const int trow = tid >> 3;          // 0..31
    const int tcol = (tid & 7) * 8;     // 0..56
    const int vswz = (tid & 7) << 3;    // == ((d>>3)&7)<<3 for d=tcol+i

    const int ntiles = 2 * qt + 2;
    for (int kt = 0; kt < ntiles; ++kt) {
        const int kbase = kt * 64;
        __syncthreads();
        // ---- stage K (natural) and V (transposed+swizzled) ----
#pragma unroll
        for (int r = 0; r < 2; ++r) {
            const int row = trow + r * 32;
            bf16x8 kv = *(const bf16x8*)(Kg + bh_off + (size_t)(kbase + row) * HD_ + tcol);
            *(bf16x8*)(Ks + row * 72 + tcol) = kv;
            union { bf16x8 v; ushort_t u[8]; } vv;
            vv.v = *(const bf16x8*)(Vg + bh_off + (size_t)(kbase + row) * HD_ + tcol);
#pragma unroll
            for (int i = 0; i < 8; ++i)
                Vt[(tcol + i) * 72 + (row ^ vswz)] = vv.u[i];
        }
        __syncthreads();

        // ---- S^T = K·Q^T: A=K (m=key), B=Q (n=q) ----
        floatx4 st[2][4];
#pragma unroll
        for (int nt = 0; nt < 4; ++nt) {
            const ushort_t* kr = Ks + (nt * 16 + l15) * 72 + quad * 8;
            bf16x8 kf0 = *(const bf16x8*)(kr);
            bf16x8 kf1 = *(const bf16x8*)(kr + 32);
#pragma unroll
            for (int g = 0; g < 2; ++g) {
                floatx4 a = {0.f, 0.f, 0.f, 0.f};
                a = __builtin_amdgcn_mfma_f32_16x16x32_bf16(kf0, qf[g][0], a, 0, 0, 0);
                a = __builtin_amdgcn_mfma_f32_16x16x32_bf16(kf1, qf[g][1], a, 0, 0, 0);
                st[g][nt] = a;
            }
        }

#pragma unroll
        for (int g = 0; g < 2; ++g) {
            const int qrow = qbase + wave * 32 + g * 16 + l15;
            // ---- scale + causal mask (skip mask on wave-uniform full tiles) ----
            if (kbase + 63 <= qbase + wave * 32 + g * 16) {
#pragma unroll
                for (int nt = 0; nt < 4; ++nt)
#pragma unroll
                    for (int r = 0; r < 4; ++r) st[g][nt][r] *= scale;
            } else {
#pragma unroll
                for (int nt = 0; nt < 4; ++nt) {
                    const int key0 = kbase + nt * 16 + quad * 4;
#pragma unroll
                    for (int r = 0; r < 4; ++r)
                        st[g][nt][r] = (key0 + r <= qrow) ? st[g][nt][r] * scale : -1e9f;
                }
            }
            // ---- online softmax: in-lane reduce + 2 shuffles ----
            floatx4 m4 = vmax4(vmax4(st[g][0], st[g][1]), vmax4(st[g][2], st[g][3]));
            float mx = fmaxf(fmaxf(m4[0], m4[1]), fmaxf(m4[2], m4[3]));
            mx = fmaxf(mx, __shfl_xor(mx, 16, 64));
            mx = fmaxf(mx, __shfl_xor(mx, 32, 64));
            const float mnew = fmaxf(m_run[g], mx);
            const float alpha = __expf(m_run[g] - mnew);
            m_run[g] = mnew;
            float sum = 0.f;
#pragma unroll
            for (int nt = 0; nt < 4; ++nt)
#pragma unroll
                for (int r = 0; r < 4; ++r) {
                    const float p = __expf(st[g][nt][r] - mnew);
                    st[g][nt][r] = p; sum += p;
                }
            sum += __shfl_xor(sum, 16, 64);
            sum += __shfl_xor(sum, 32, 64);
            l_run[g] = l_run[g] * alpha + sum;
#pragma unroll
            for (int nt = 0; nt < 4; ++nt) {
                o_acc[g][nt][0] *= alpha; o_acc[g][nt][1] *= alpha;
                o_acc[g][nt][2] *= alpha; o_acc[g][nt][3] *= alpha;
            }
            // ---- pack P^T -> wave-private LDS [q][key] (b64 stores) ----
            ushort_t* pr = &Pt[wave][(g * 16 + l15) * 72 + quad * 4];
#pragma unroll
            for (int nt = 0; nt < 4; ++nt) {
                uint2 pk;
                pk.x = pack_bf16_trunc(st[g][nt][0], st[g][nt][1]);
                pk.y = pack_bf16_trunc(st[g][nt][2], st[g][nt][3]);
                *(uint2*)(pr + nt * 16) = pk;
            }
        }
        // intra-wave LDS write->read ordering (DS is in-order per wave)
        __builtin_amdgcn_fence(__ATOMIC_ACQ_REL, "wavefront");
        __builtin_amdgcn_wave_barrier();

        // ---- O^T += V^T·P^T: A=V^T (m=d), B=P^T (n=q) ----
#pragma unroll
        for (int g = 0; g < 2; ++g) {
            const ushort_t* prr = &Pt[wave][(g * 16 + l15) * 72];
            bf16x8 pf0 = *(const bf16x8*)(prr + quad * 8);
            bf16x8 pf1 = *(const bf16x8*)(prr + 32 + quad * 8);
#pragma unroll
            for (int dt = 0; dt < 4; ++dt) {
                const int d = dt * 16 + l15;
                const int sw = ((d >> 3) & 7) << 3;
                const ushort_t* vr = Vt + d * 72;
                bf16x8 vf0 = *(const bf16x8*)(vr + ((quad * 8) ^ sw));
                bf16x8 vf1 = *(const bf16x8*)(vr + ((32 + quad * 8) ^ sw));
                o_acc[g][dt] = __builtin_amdgcn_mfma_f32_16x16x32_bf16(vf0, pf0, o_acc[g][dt], 0, 0, 0);
                o_acc[g][dt] = __builtin_amdgcn_mfma_f32_16x16x32_bf16(vf1, pf1, o_acc[g][dt], 0, 0, 0);
            }
        }
    }

    // ---- epilogue: normalize, write bf16 (B,S,H*64), b64 stores ----
    const int b = bh >> 4, h = bh & 15;
#pragma unroll
    for (int g = 0; g < 2; ++g) {
        const int q = qbase + wave * 32 + g * 16 + l15;
        const float inv = 1.0f / l_run[g];
        ushort_t* orow = Og + ((size_t)(b * S_ + q)) * DM_ + h * HD_ + quad * 4;
#pragma unroll
        for (int dt = 0; dt < 4; ++dt) {
            ushort_t u0 = f2bf(o_acc[g][dt][0] * inv);
            ushort_t u1 = f2bf(o_acc[g][dt][1] * inv);
            ushort_t u2 = f2bf(o_acc[g][dt][2] * inv);
            ushort_t u3 = f2bf(o_acc[g][dt][3] * inv);
            uint2 pk;
            pk.x = (unsigned int)u0 | ((unsigned int)u1 << 16);
            pk.y = (unsigned int)u2 | ((unsigned int)u3 << 16);
            *(uint2*)(orow + dt * 16) = pk;
        }
    }
}

// ---------------------------------------------------------------------------
extern "C" void kernel_launch(void* const* d_in, const int* in_sizes, int n_in,
                              void* d_out, int out_size, void* d_ws, size_t ws_size,
                              hipStream_t stream)
{
    const float* x  = (const float*)d_in[0];
    const float* cf = (const float*)d_in[1];
    const float* sf = (const float*)d_in[2];
    // d_in[3] = causal_mask: computed analytically, never read
    const float* wq = (const float*)d_in[4];
    const float* wk = (const float*)d_in[5];
    const float* wv = (const float*)d_in[6];
    const float* wo = (const float*)d_in[7];
    float* out = (float*)d_out;

    const size_t NELEM = (size_t)B_ * S_ * DM_;   // 8388608
    const size_t WELEM = (size_t)DM_ * DM_;       // 1048576
    ushort_t* xb  = (ushort_t*)d_ws;
    ushort_t* qb  = xb + NELEM;
    ushort_t* kb  = qb + NELEM;
    ushort_t* vb  = kb + NELEM;
    ushort_t* ao  = vb + NELEM;
    ushort_t* wqb = ao + NELEM;
    ushort_t* wkb = wqb + WELEM;
    ushort_t* wvb = wkb + WELEM;
    ushort_t* wob = wvb + WELEM;

    cvt_kernel<<<dim3(NELEM / 1024), 256, 0, stream>>>(x,  xb);
    cvt_kernel<<<dim3(WELEM / 1024), 256, 0, stream>>>(wq, wqb);
    cvt_kernel<<<dim3(WELEM / 1024), 256, 0, stream>>>(wk, wkb);
    cvt_kernel<<<dim3(WELEM / 1024), 256, 0, stream>>>(wv, wvb);
    cvt_kernel<<<dim3(WELEM / 1024), 256, 0, stream>>>(wo, wob);

    const int M = B_ * S_;
    dim3 ggrid(M / 128, DM_ / 128);
    gemm_bt_kernel<<<ggrid, 256, 0, stream>>>(xb, wqb, qb, M, DM_, DM_, 0);
    gemm_bt_kernel<<<ggrid, 256, 0, stream>>>(xb, wkb, kb, M, DM_, DM_, 0);
    gemm_bt_kernel<<<ggrid, 256, 0, stream>>>(xb, wvb, vb, M, DM_, DM_, 0);
    rope_kernel<<<dim3((B_ * NH_ * S_ * 32) / 256), 256, 0, stream>>>(qb, kb, cf, sf);
    attn_kernel<<<dim3(S_ / 128, B_ * NH_), 256, 0, stream>>>(qb, kb, vb, ao);
    gemm_bt_kernel<<<ggrid, 256, 0, stream>>>(ao, wob, out, M, DM_, DM_, 1);
}

// Round 4
// 303.029 us; speedup vs baseline: 1.6363x; 1.5242x over previous
//
#include <hip/hip_runtime.h>
#include <stdint.h>

#define B_  4
#define S_  2048
#define DM_ 1024
#define NH_ 16
#define HD_ 64

typedef unsigned short ushort_t;
typedef __bf16 bf16x8 __attribute__((ext_vector_type(8)));
typedef float  floatx4 __attribute__((ext_vector_type(4)));
typedef float  floatx16 __attribute__((ext_vector_type(16)));

__device__ __forceinline__ float bf2f(ushort_t u) {
    union { unsigned int i; float f; } v; v.i = ((unsigned int)u) << 16; return v.f;
}
__device__ __forceinline__ ushort_t f2bf(float f) {
    union { float f; unsigned int i; } v; v.f = f;
    unsigned int x = v.i;
    return (ushort_t)((x + 0x7fffu + ((x >> 16) & 1u)) >> 16);
}
__device__ __forceinline__ unsigned int pack_bf16_trunc(float lo, float hi) {
    union { float f; unsigned int u; } a, b;
    a.f = lo; b.f = hi;
    return __builtin_amdgcn_perm(b.u, a.u, 0x07060302u);
}

// ---------------------------------------------------------------------------
// f32 -> bf16 conversions
// ---------------------------------------------------------------------------
__global__ __launch_bounds__(256) void cvt_kernel(
    const float* __restrict__ src, ushort_t* __restrict__ dst)
{
    const int i = blockIdx.x * 256 + threadIdx.x;
    float4 v = ((const float4*)src)[i];
    ushort4 o; o.x = f2bf(v.x); o.y = f2bf(v.y); o.z = f2bf(v.z); o.w = f2bf(v.w);
    ((ushort4*)dst)[i] = o;
}

__global__ __launch_bounds__(256) void cvt4_kernel(
    const float* __restrict__ s0, const float* __restrict__ s1,
    const float* __restrict__ s2, const float* __restrict__ s3,
    ushort_t* __restrict__ d0, ushort_t* __restrict__ d1,
    ushort_t* __restrict__ d2, ushort_t* __restrict__ d3)
{
    const int z = blockIdx.y;
    const float* s = z == 0 ? s0 : z == 1 ? s1 : z == 2 ? s2 : s3;
    ushort_t*   d = z == 0 ? d0 : z == 1 ? d1 : z == 2 ? d2 : d3;
    const int i = blockIdx.x * 256 + threadIdx.x;
    float4 v = ((const float4*)s)[i];
    ushort4 o; o.x = f2bf(v.x); o.y = f2bf(v.y); o.z = f2bf(v.z); o.w = f2bf(v.w);
    ((ushort4*)d)[i] = o;
}

// ---------------------------------------------------------------------------
// GEMM: C = A @ B^T (m97 structure). blockIdx.z selects weight/output set.
// mode 0: bf16 out -> (B,H,S,64) head-major; mode 1: f32 out row-major
// ---------------------------------------------------------------------------
__global__ __launch_bounds__(256) void gemm_bt_kernel(
    const ushort_t* __restrict__ A,
    const ushort_t* __restrict__ B0, const ushort_t* __restrict__ B1,
    const ushort_t* __restrict__ B2,
    void* __restrict__ C0, void* __restrict__ C1, void* __restrict__ C2,
    int M, int N, int K, int mode)
{
    __shared__ ushort_t As[128 * 32];
    __shared__ ushort_t Bs[128 * 32];
    const int z = blockIdx.z;
    const ushort_t* Bw = z == 0 ? B0 : z == 1 ? B1 : B2;
    void* Cv           = z == 0 ? C0 : z == 1 ? C1 : C2;

    const int tid  = threadIdx.x;
    const int mbase = blockIdx.x * 128;
    const int nbase = blockIdx.y * 128;
    const int wave = tid >> 6, lane = tid & 63;
    const int l15 = lane & 15, quad = lane >> 4;
    const int wm = (wave & 1) * 64, wn = (wave >> 1) * 64;

    floatx4 acc[4][4] = {};

    const int e0   = tid * 8;
    const int row0 = e0 >> 5;
    const int col0 = e0 & 31;

    for (int kt = 0; kt < K; kt += 32) {
        __syncthreads();
#pragma unroll
        for (int r = 0; r < 2; ++r) {
            const int e   = e0 + r * 2048;
            const int row = row0 + r * 64;
            const ushort_t* ga = A  + (size_t)(mbase + row) * K + kt + col0;
            const ushort_t* gb = Bw + (size_t)(nbase + row) * K + kt + col0;
            __builtin_amdgcn_global_load_lds(
                (const __attribute__((address_space(1))) unsigned int*)ga,
                (__attribute__((address_space(3))) unsigned int*)(As + e), 16, 0, 0);
            __builtin_amdgcn_global_load_lds(
                (const __attribute__((address_space(1))) unsigned int*)gb,
                (__attribute__((address_space(3))) unsigned int*)(Bs + e), 16, 0, 0);
        }
        __builtin_amdgcn_s_waitcnt(0);
        __syncthreads();

        bf16x8 af[4], bfr[4];
#pragma unroll
        for (int t = 0; t < 4; ++t) {
            af[t]  = *(const bf16x8*)(As + (wm + t * 16 + l15) * 32 + quad * 8);
            bfr[t] = *(const bf16x8*)(Bs + (wn + t * 16 + l15) * 32 + quad * 8);
        }
#pragma unroll
        for (int mt = 0; mt < 4; ++mt)
#pragma unroll
            for (int nt = 0; nt < 4; ++nt)
                acc[mt][nt] = __builtin_amdgcn_mfma_f32_16x16x32_bf16(
                    af[mt], bfr[nt], acc[mt][nt], 0, 0, 0);
    }

#pragma unroll
    for (int mt = 0; mt < 4; ++mt) {
#pragma unroll
        for (int nt = 0; nt < 4; ++nt) {
            const int col = nbase + wn + nt * 16 + l15;
#pragma unroll
            for (int r = 0; r < 4; ++r) {
                const int m = mbase + wm + mt * 16 + quad * 4 + r;
                if (mode == 0) {
                    const int b = m >> 11, s = m & 2047;
                    const int hh = col >> 6, d = col & 63;
                    ((ushort_t*)Cv)[(((size_t)(b * NH_ + hh)) * S_ + s) * HD_ + d] =
                        f2bf(acc[mt][nt][r]);
                } else {
                    ((float*)Cv)[(size_t)m * N + col] = acc[mt][nt][r];
                }
            }
        }
    }
}

// ---------------------------------------------------------------------------
// RoPE on Q and K in (B,H,S,64) bf16. Q is pre-scaled by 1/sqrt(64)=0.125
// (exact in bf16: exponent shift) so attention needs no S-scaling.
// ---------------------------------------------------------------------------
__global__ __launch_bounds__(256) void rope_kernel(
    ushort_t* __restrict__ q, ushort_t* __restrict__ k,
    const float* __restrict__ cf, const float* __restrict__ sf)
{
    const int idx = blockIdx.x * 256 + threadIdx.x;
    const int j = idx & 31;
    const int s = (idx >> 5) & (S_ - 1);
    const float c  = cf[s * 32 + j];
    const float sn = sf[s * 32 + j];
    const size_t base = (size_t)idx * 2;
    float qe = bf2f(q[base]), qo = bf2f(q[base + 1]);
    q[base]     = f2bf((qe * c - qo * sn) * 0.125f);
    q[base + 1] = f2bf((qe * sn + qo * c) * 0.125f);
    float ke = bf2f(k[base]), ko = bf2f(k[base + 1]);
    k[base]     = f2bf(ke * c - ko * sn);
    k[base + 1] = f2bf(ke * sn + ko * c);
}

// ---------------------------------------------------------------------------
// Causal flash attention, S^T/O^T with 32x32x16 MFMA.
// Block = 256 thr (4 waves), each wave owns 32 q-rows (BQ=128).
// Pairing: block processes q-tiles {p, 15-p} sequentially -> uniform 34 tiles.
// S^T = K·Q^T (A=K, B=Q): C col=q=lane&31, row=key=(reg&3)+8*(reg>>2)+4*(lane>>5)
// O^T = V^T·P^T; P^T round-trips wave-private LDS (intra-wave, no barrier).
// ---------------------------------------------------------------------------
__global__ __launch_bounds__(256, 2) void attn_kernel(
    const ushort_t* __restrict__ Qg, const ushort_t* __restrict__ Kg,
    const ushort_t* __restrict__ Vg, ushort_t* __restrict__ Og)
{
    __shared__ ushort_t Ks[64 * 72];       // [key][dim]
    __shared__ ushort_t Vt[64 * 72];       // [dim][key ^ swizzle]
    __shared__ ushort_t Pt[4][32 * 72];    // per-wave P^T as [q][key]

    const int pair = blockIdx.x;           // 0..7
    const int bh   = blockIdx.y;
    const int tid  = threadIdx.x;
    const int wave = tid >> 6, lane = tid & 63;
    const int l31 = lane & 31, h = lane >> 5;

    const size_t bh_off = (size_t)bh * S_ * HD_;
    const int trow = tid >> 3;             // 0..31
    const int tcol = (tid & 7) * 8;        // 0..56
    const int vswz = (tid & 7) << 3;
    const int b_out = bh >> 4, h_out = bh & 15;

#pragma unroll 1
    for (int seg = 0; seg < 2; ++seg) {
        const int qtile = seg ? (15 - pair) : pair;
        const int qbase = qtile * 128;
        const int nkt   = 2 * qtile + 2;
        const int qrow  = qbase + wave * 32 + l31;

        bf16x8 qf[4];
#pragma unroll
        for (int ks = 0; ks < 4; ++ks)
            qf[ks] = *(const bf16x8*)(Qg + bh_off + (size_t)qrow * HD_ + ks * 16 + h * 8);

        float m_run = -1e30f, l_run = 0.f;
        floatx16 o_acc[2] = {};

        for (int kt = 0; kt < nkt; ++kt) {
            const int kbase = kt * 64;
            __syncthreads();
            // ---- stage K (natural) and V (transposed + chunk swizzle) ----
#pragma unroll
            for (int r = 0; r < 2; ++r) {
                const int row = trow + r * 32;
                *(bf16x8*)(Ks + row * 72 + tcol) =
                    *(const bf16x8*)(Kg + bh_off + (size_t)(kbase + row) * HD_ + tcol);
                union { bf16x8 v; ushort_t u[8]; } vv;
                vv.v = *(const bf16x8*)(Vg + bh_off + (size_t)(kbase + row) * HD_ + tcol);
#pragma unroll
                for (int i = 0; i < 8; ++i)
                    Vt[(tcol + i) * 72 + (row ^ vswz)] = vv.u[i];
            }
            __syncthreads();

            // waves whose rows are all < kbase: tile fully masked -> skip
            if (kbase > qbase + wave * 32 + 31) continue;

            // ---- S^T = K·Q^T ----
            floatx16 st[2] = {};
#pragma unroll
            for (int nt = 0; nt < 2; ++nt) {
                const ushort_t* kr = Ks + (nt * 32 + l31) * 72 + h * 8;
#pragma unroll
                for (int ks = 0; ks < 4; ++ks) {
                    bf16x8 kf = *(const bf16x8*)(kr + ks * 16);
                    st[nt] = __builtin_amdgcn_mfma_f32_32x32x16_bf16(kf, qf[ks], st[nt], 0, 0, 0);
                }
            }
            // ---- causal mask (only diagonal tiles; Q pre-scaled) ----
            if (kbase + 63 > qbase + wave * 32) {
#pragma unroll
                for (int nt = 0; nt < 2; ++nt) {
                    const int key0 = kbase + nt * 32 + 4 * h;
#pragma unroll
                    for (int c = 0; c < 4; ++c)
#pragma unroll
                        for (int r = 0; r < 4; ++r)
                            if (key0 + 8 * c + r > qrow) st[nt][c * 4 + r] = -1e9f;
                }
            }
            // ---- online softmax (q per-lane; one cross-lane hop) ----
            float mx = st[0][0];
#pragma unroll
            for (int nt = 0; nt < 2; ++nt)
#pragma unroll
                for (int i = 0; i < 16; ++i) mx = fmaxf(mx, st[nt][i]);
            mx = fmaxf(mx, __shfl_xor(mx, 32, 64));
            const float mnew = fmaxf(m_run, mx);
            const float alpha = __expf(m_run - mnew);
            m_run = mnew;
            float sum = 0.f;
#pragma unroll
            for (int nt = 0; nt < 2; ++nt)
#pragma unroll
                for (int i = 0; i < 16; ++i) {
                    const float p = __expf(st[nt][i] - mnew);
                    st[nt][i] = p; sum += p;
                }
            sum += __shfl_xor(sum, 32, 64);
            l_run = l_run * alpha + sum;
#pragma unroll
            for (int dt = 0; dt < 2; ++dt)
#pragma unroll
                for (int i = 0; i < 16; ++i) o_acc[dt][i] *= alpha;

            // ---- P^T -> wave-private LDS [q][key] (b64 stores) ----
            ushort_t* pr = &Pt[wave][l31 * 72 + 4 * h];
#pragma unroll
            for (int nt = 0; nt < 2; ++nt)
#pragma unroll
                for (int c = 0; c < 4; ++c) {
                    uint2 pk;
                    pk.x = pack_bf16_trunc(st[nt][c * 4 + 0], st[nt][c * 4 + 1]);
                    pk.y = pack_bf16_trunc(st[nt][c * 4 + 2], st[nt][c * 4 + 3]);
                    *(uint2*)(pr + nt * 32 + 8 * c) = pk;
                }
            __builtin_amdgcn_fence(__ATOMIC_ACQ_REL, "wavefront");
            __builtin_amdgcn_wave_barrier();

            bf16x8 pf[4];
#pragma unroll
            for (int ks = 0; ks < 4; ++ks)
                pf[ks] = *(const bf16x8*)(&Pt[wave][l31 * 72 + ks * 16 + h * 8]);

            // ---- O^T += V^T·P^T ----
#pragma unroll
            for (int dt = 0; dt < 2; ++dt) {
                const int d = dt * 32 + l31;
                const int sw = ((d >> 3) & 7) << 3;
                const ushort_t* vr = Vt + d * 72;
#pragma unroll
                for (int ks = 0; ks < 4; ++ks) {
                    bf16x8 vf = *(const bf16x8*)(vr + ((ks * 16 + h * 8) ^ sw));
                    o_acc[dt] = __builtin_amdgcn_mfma_f32_32x32x16_bf16(vf, pf[ks], o_acc[dt], 0, 0, 0);
                }
            }
        }

        // ---- epilogue: normalize, write bf16 (B,S,H*64) ----
        const float inv = 1.0f / l_run;
        ushort_t* orow = Og + ((size_t)(b_out * S_ + qrow)) * DM_ + h_out * HD_;
#pragma unroll
        for (int dt = 0; dt < 2; ++dt)
#pragma unroll
            for (int c = 0; c < 4; ++c) {
                uint2 pk;
                pk.x = (unsigned)f2bf(o_acc[dt][c * 4 + 0] * inv) |
                       ((unsigned)f2bf(o_acc[dt][c * 4 + 1] * inv) << 16);
                pk.y = (unsigned)f2bf(o_acc[dt][c * 4 + 2] * inv) |
                       ((unsigned)f2bf(o_acc[dt][c * 4 + 3] * inv) << 16);
                *(uint2*)(orow + dt * 32 + 8 * c + 4 * h) = pk;
            }
    }
}

// ---------------------------------------------------------------------------
extern "C" void kernel_launch(void* const* d_in, const int* in_sizes, int n_in,
                              void* d_out, int out_size, void* d_ws, size_t ws_size,
                              hipStream_t stream)
{
    const float* x  = (const float*)d_in[0];
    const float* cf = (const float*)d_in[1];
    const float* sf = (const float*)d_in[2];
    // d_in[3] = causal_mask: computed analytically, never read
    const float* wq = (const float*)d_in[4];
    const float* wk = (const float*)d_in[5];
    const float* wv = (const float*)d_in[6];
    const float* wo = (const float*)d_in[7];
    float* out = (float*)d_out;

    const size_t NELEM = (size_t)B_ * S_ * DM_;   // 8388608
    const size_t WELEM = (size_t)DM_ * DM_;       // 1048576
    ushort_t* xb  = (ushort_t*)d_ws;
    ushort_t* qb  = xb + NELEM;
    ushort_t* kb  = qb + NELEM;
    ushort_t* vb  = kb + NELEM;
    ushort_t* ao  = vb + NELEM;
    ushort_t* wqb = ao + NELEM;
    ushort_t* wkb = wqb + WELEM;
    ushort_t* wvb = wkb + WELEM;
    ushort_t* wob = wvb + WELEM;

    cvt_kernel<<<dim3(NELEM / 1024), 256, 0, stream>>>(x, xb);
    cvt4_kernel<<<dim3(WELEM / 1024, 4), 256, 0, stream>>>(
        wq, wk, wv, wo, wqb, wkb, wvb, wob);

    const int M = B_ * S_;
    // fused QKV: grid.z selects weight/output
    gemm_bt_kernel<<<dim3(M / 128, DM_ / 128, 3), 256, 0, stream>>>(
        xb, wqb, wkb, wvb, qb, kb, vb, M, DM_, DM_, 0);
    rope_kernel<<<dim3((B_ * NH_ * S_ * 32) / 256), 256, 0, stream>>>(qb, kb, cf, sf);
    attn_kernel<<<dim3(8, B_ * NH_), 256, 0, stream>>>(qb, kb, vb, ao);
    gemm_bt_kernel<<<dim3(M / 128, DM_ / 128, 1), 256, 0, stream>>>(
        ao, wob, wob, wob, out, out, out, M, DM_, DM_, 1);
}

// Round 5
// 285.797 us; speedup vs baseline: 1.7350x; 1.0603x over previous
//
#include <hip/hip_runtime.h>
#include <stdint.h>

#define B_  4
#define S_  2048
#define DM_ 1024
#define NH_ 16
#define HD_ 64

typedef unsigned short ushort_t;
typedef __bf16 bf16x8 __attribute__((ext_vector_type(8)));
typedef float  floatx4 __attribute__((ext_vector_type(4)));
typedef float  floatx16 __attribute__((ext_vector_type(16)));

__device__ __forceinline__ float bf2f(ushort_t u) {
    union { unsigned int i; float f; } v; v.i = ((unsigned int)u) << 16; return v.f;
}
__device__ __forceinline__ ushort_t f2bf(float f) {
    union { float f; unsigned int i; } v; v.f = f;
    unsigned int x = v.i;
    return (ushort_t)((x + 0x7fffu + ((x >> 16) & 1u)) >> 16);
}
__device__ __forceinline__ unsigned int pack_bf16_trunc(float lo, float hi) {
    union { float f; unsigned int u; } a, b;
    a.f = lo; b.f = hi;
    return __builtin_amdgcn_perm(b.u, a.u, 0x07060302u);
}

// ---------------------------------------------------------------------------
// fused f32 -> bf16 conversion: x (8192 blocks) + 4 weights (1024 each)
// ---------------------------------------------------------------------------
__global__ __launch_bounds__(256) void cvt_all_kernel(
    const float* __restrict__ x,  const float* __restrict__ wq,
    const float* __restrict__ wk, const float* __restrict__ wv,
    const float* __restrict__ wo,
    ushort_t* __restrict__ xb,  ushort_t* __restrict__ wqb,
    ushort_t* __restrict__ wkb, ushort_t* __restrict__ wvb,
    ushort_t* __restrict__ wob)
{
    const int blk = blockIdx.x;
    const float* src; ushort_t* dst; int off;
    if (blk < 8192)       { src = x;  dst = xb;  off = blk; }
    else if (blk < 9216)  { src = wq; dst = wqb; off = blk - 8192; }
    else if (blk < 10240) { src = wk; dst = wkb; off = blk - 9216; }
    else if (blk < 11264) { src = wv; dst = wvb; off = blk - 10240; }
    else                  { src = wo; dst = wob; off = blk - 11264; }
    const int i = off * 256 + threadIdx.x;
    float4 v = ((const float4*)src)[i];
    ushort4 o; o.x = f2bf(v.x); o.y = f2bf(v.y); o.z = f2bf(v.z); o.w = f2bf(v.w);
    ((ushort4*)dst)[i] = o;
}

// ---------------------------------------------------------------------------
// GEMM: C = A @ B^T, BK=64 via two stacked BK=32 LDS panels (rows stay 64 B:
// preserves m97 bank pattern AND global_load_lds lane-contiguity).
// z selects weight/output. Epilogues:
//   mode 0, z=0/1: bf16 -> (B,H,S,64) scatter (Q,K)
//   mode 0, z=2  : bf16 -> (B,H,64,S) V^T, b64-packed along s
//   mode 1       : f32  -> row-major
// ---------------------------------------------------------------------------
__global__ __launch_bounds__(256) void gemm_bt_kernel(
    const ushort_t* __restrict__ A,
    const ushort_t* __restrict__ B0, const ushort_t* __restrict__ B1,
    const ushort_t* __restrict__ B2,
    void* __restrict__ C0, void* __restrict__ C1, void* __restrict__ C2,
    int M, int N, int K, int mode)
{
    __shared__ ushort_t As[128 * 64];   // [kk][row][32]
    __shared__ ushort_t Bs[128 * 64];
    const int z = blockIdx.z;
    const ushort_t* Bw = z == 0 ? B0 : z == 1 ? B1 : B2;
    void* Cv           = z == 0 ? C0 : z == 1 ? C1 : C2;

    const int tid  = threadIdx.x;
    const int mbase = blockIdx.x * 128;
    const int nbase = blockIdx.y * 128;
    const int wave = tid >> 6, lane = tid & 63;
    const int l15 = lane & 15, quad = lane >> 4;
    const int wm = (wave & 1) * 64, wn = (wave >> 1) * 64;

    floatx4 acc[4][4] = {};

    for (int kt = 0; kt < K; kt += 64) {
        __syncthreads();
#pragma unroll
        for (int r = 0; r < 4; ++r) {
            const int e   = tid * 8 + r * 2048;
            const int kk  = e >> 12;           // panel
            const int row = (e >> 5) & 127;
            const int c   = e & 31;
            const ushort_t* ga = A  + (size_t)(mbase + row) * K + kt + kk * 32 + c;
            const ushort_t* gb = Bw + (size_t)(nbase + row) * K + kt + kk * 32 + c;
            __builtin_amdgcn_global_load_lds(
                (const __attribute__((address_space(1))) unsigned int*)ga,
                (__attribute__((address_space(3))) unsigned int*)(As + e), 16, 0, 0);
            __builtin_amdgcn_global_load_lds(
                (const __attribute__((address_space(1))) unsigned int*)gb,
                (__attribute__((address_space(3))) unsigned int*)(Bs + e), 16, 0, 0);
        }
        __builtin_amdgcn_s_waitcnt(0);
        __syncthreads();

#pragma unroll
        for (int kk = 0; kk < 2; ++kk) {
            bf16x8 af[4], bfr[4];
#pragma unroll
            for (int t = 0; t < 4; ++t) {
                af[t]  = *(const bf16x8*)(As + kk * 4096 + (wm + t * 16 + l15) * 32 + quad * 8);
                bfr[t] = *(const bf16x8*)(Bs + kk * 4096 + (wn + t * 16 + l15) * 32 + quad * 8);
            }
#pragma unroll
            for (int mt = 0; mt < 4; ++mt)
#pragma unroll
                for (int nt = 0; nt < 4; ++nt)
                    acc[mt][nt] = __builtin_amdgcn_mfma_f32_16x16x32_bf16(
                        af[mt], bfr[nt], acc[mt][nt], 0, 0, 0);
        }
    }

    const bool vtmode = (mode == 0) && (z == 2);
#pragma unroll
    for (int mt = 0; mt < 4; ++mt) {
#pragma unroll
        for (int nt = 0; nt < 4; ++nt) {
            const int col = nbase + wn + nt * 16 + l15;
            const int m0  = mbase + wm + mt * 16 + quad * 4;
            if (vtmode) {
                const int b = m0 >> 11, s = m0 & 2047;
                const int hh = col >> 6, d = col & 63;
                uint2 pk;
                pk.x = (unsigned)f2bf(acc[mt][nt][0]) | ((unsigned)f2bf(acc[mt][nt][1]) << 16);
                pk.y = (unsigned)f2bf(acc[mt][nt][2]) | ((unsigned)f2bf(acc[mt][nt][3]) << 16);
                *(uint2*)&((ushort_t*)Cv)[((size_t)((b * NH_ + hh) * HD_ + d)) * S_ + s] = pk;
            } else if (mode == 0) {
#pragma unroll
                for (int r = 0; r < 4; ++r) {
                    const int m = m0 + r;
                    const int b = m >> 11, s = m & 2047;
                    const int hh = col >> 6, d = col & 63;
                    ((ushort_t*)Cv)[(((size_t)(b * NH_ + hh)) * S_ + s) * HD_ + d] =
                        f2bf(acc[mt][nt][r]);
                }
            } else {
#pragma unroll
                for (int r = 0; r < 4; ++r)
                    ((float*)Cv)[(size_t)(m0 + r) * N + col] = acc[mt][nt][r];
            }
        }
    }
}

// ---------------------------------------------------------------------------
// RoPE on Q,K (B,H,S,64) bf16. Q pre-scaled by (1/8)*log2(e) so attention
// softmax runs in exp2 domain with no extra multiplies.
// ---------------------------------------------------------------------------
#define QSCALE 0.1803368801f   // 0.125 * log2(e)
__global__ __launch_bounds__(256) void rope_kernel(
    ushort_t* __restrict__ q, ushort_t* __restrict__ k,
    const float* __restrict__ cf, const float* __restrict__ sf)
{
    const int idx = blockIdx.x * 256 + threadIdx.x;
    const int j = idx & 31;
    const int s = (idx >> 5) & (S_ - 1);
    const float c  = cf[s * 32 + j];
    const float sn = sf[s * 32 + j];
    const size_t base = (size_t)idx * 2;
    float qe = bf2f(q[base]), qo = bf2f(q[base + 1]);
    q[base]     = f2bf((qe * c - qo * sn) * QSCALE);
    q[base + 1] = f2bf((qe * sn + qo * c) * QSCALE);
    float ke = bf2f(k[base]), ko = bf2f(k[base + 1]);
    k[base]     = f2bf(ke * c - ko * sn);
    k[base + 1] = f2bf(ke * sn + ko * c);
}

// ---------------------------------------------------------------------------
// Causal flash attention, S^T/O^T with 32x32x16 MFMA, exp2-domain softmax.
// Q,K in (B,H,S,64); V in (B,H,64,S) (pre-transposed by GEMM epilogue) ->
// V^T staging is pure b128 (no scalar transpose). P^T swizzled, unpadded.
// Block = 4 waves x 32 q-rows; pairs {p,15-p} for uniform 34 tiles.
// ---------------------------------------------------------------------------
__global__ __launch_bounds__(256, 2) void attn_kernel(
    const ushort_t* __restrict__ Qg, const ushort_t* __restrict__ Kg,
    const ushort_t* __restrict__ Vg, ushort_t* __restrict__ Og)
{
    __shared__ ushort_t Ks[64 * 72];       // [key][dim], pad 72
    __shared__ ushort_t Vt[64 * 72];       // [dim][key ^ chunk-swizzle], pad 72
    __shared__ ushort_t Pt[4][32 * 64];    // per-wave P^T [q][key ^ swizzle]

    const int pair = blockIdx.x;           // 0..7
    const int bh   = blockIdx.y;
    const int tid  = threadIdx.x;
    const int wave = tid >> 6, lane = tid & 63;
    const int l31 = lane & 31, h = lane >> 5;

    const size_t bh_off = (size_t)bh * S_ * HD_;
    const int trow = tid >> 3;             // 0..31
    const int tcol = (tid & 7) * 8;        // 0..56
    const int pswz = (l31 & 7) << 3;
    const int b_out = bh >> 4, h_out = bh & 15;

#pragma unroll 1
    for (int seg = 0; seg < 2; ++seg) {
        const int qtile = seg ? (15 - pair) : pair;
        const int qbase = qtile * 128;
        const int nkt   = 2 * qtile + 2;
        const int qrow  = qbase + wave * 32 + l31;

        bf16x8 qf[4];
#pragma unroll
        for (int ks = 0; ks < 4; ++ks)
            qf[ks] = *(const bf16x8*)(Qg + bh_off + (size_t)qrow * HD_ + ks * 16 + h * 8);

        float m_run = -1e30f, l_run = 0.f;
        floatx16 o_acc[2] = {};

        for (int kt = 0; kt < nkt; ++kt) {
            const int kbase = kt * 64;
            __syncthreads();
            // ---- stage K [key][dim] and V^T [dim][key^swz] — all b128 ----
#pragma unroll
            for (int r = 0; r < 2; ++r) {
                const int row = trow + r * 32;
                *(bf16x8*)(Ks + row * 72 + tcol) =
                    *(const bf16x8*)(Kg + bh_off + (size_t)(kbase + row) * HD_ + tcol);
                const int c = tid + r * 256;
                const int d = c >> 3, k0 = (c & 7) * 8;
                bf16x8 vv = *(const bf16x8*)(Vg + bh_off + (size_t)d * S_ + kbase + k0);
                *(bf16x8*)(Vt + d * 72 + (k0 ^ (((d >> 3) & 7) << 3))) = vv;
            }
            __syncthreads();

            // fully-masked tile for this wave -> skip compute
            if (kbase > qbase + wave * 32 + 31) continue;

            // ---- S^T = K·Q^T ----
            floatx16 st[2] = {};
#pragma unroll
            for (int nt = 0; nt < 2; ++nt) {
                const ushort_t* kr = Ks + (nt * 32 + l31) * 72 + h * 8;
#pragma unroll
                for (int ks = 0; ks < 4; ++ks) {
                    bf16x8 kf = *(const bf16x8*)(kr + ks * 16);
                    st[nt] = __builtin_amdgcn_mfma_f32_32x32x16_bf16(kf, qf[ks], st[nt], 0, 0, 0);
                }
            }
            // ---- causal mask (diagonal tiles only; Q pre-scaled) ----
            if (kbase + 63 > qbase + wave * 32) {
#pragma unroll
                for (int nt = 0; nt < 2; ++nt) {
                    const int key0 = kbase + nt * 32 + 4 * h;
#pragma unroll
                    for (int c = 0; c < 4; ++c)
#pragma unroll
                        for (int r = 0; r < 4; ++r)
                            if (key0 + 8 * c + r > qrow) st[nt][c * 4 + r] = -1e9f;
                }
            }
            // ---- online softmax, exp2 domain ----
            float mx = st[0][0];
#pragma unroll
            for (int nt = 0; nt < 2; ++nt)
#pragma unroll
                for (int i = 0; i < 16; ++i) mx = fmaxf(mx, st[nt][i]);
            mx = fmaxf(mx, __shfl_xor(mx, 32, 64));
            const float mnew = fmaxf(m_run, mx);
            const float alpha = __builtin_amdgcn_exp2f(m_run - mnew);
            m_run = mnew;
            float sum = 0.f;
#pragma unroll
            for (int nt = 0; nt < 2; ++nt)
#pragma unroll
                for (int i = 0; i < 16; ++i) {
                    const float p = __builtin_amdgcn_exp2f(st[nt][i] - mnew);
                    st[nt][i] = p; sum += p;
                }
            sum += __shfl_xor(sum, 32, 64);
            l_run = l_run * alpha + sum;
#pragma unroll
            for (int dt = 0; dt < 2; ++dt)
#pragma unroll
                for (int i = 0; i < 16; ++i) o_acc[dt][i] *= alpha;

            // ---- P^T -> wave-private LDS [q][key^swz] (b64 stores) ----
            ushort_t* pr = &Pt[wave][l31 * 64];
#pragma unroll
            for (int nt = 0; nt < 2; ++nt)
#pragma unroll
                for (int c = 0; c < 4; ++c) {
                    uint2 pk;
                    pk.x = pack_bf16_trunc(st[nt][c * 4 + 0], st[nt][c * 4 + 1]);
                    pk.y = pack_bf16_trunc(st[nt][c * 4 + 2], st[nt][c * 4 + 3]);
                    *(uint2*)(pr + (((nt * 32 + 8 * c) ^ pswz) + 4 * h)) = pk;
                }
            __builtin_amdgcn_fence(__ATOMIC_ACQ_REL, "wavefront");
            __builtin_amdgcn_wave_barrier();

            bf16x8 pf[4];
#pragma unroll
            for (int ks = 0; ks < 4; ++ks)
                pf[ks] = *(const bf16x8*)(&Pt[wave][l31 * 64 + ((ks * 16 + h * 8) ^ pswz)]);

            // ---- O^T += V^T·P^T ----
#pragma unroll
            for (int dt = 0; dt < 2; ++dt) {
                const int d = dt * 32 + l31;
                const int sw = ((d >> 3) & 7) << 3;
                const ushort_t* vr = Vt + d * 72;
#pragma unroll
                for (int ks = 0; ks < 4; ++ks) {
                    bf16x8 vf = *(const bf16x8*)(vr + ((ks * 16 + h * 8) ^ sw));
                    o_acc[dt] = __builtin_amdgcn_mfma_f32_32x32x16_bf16(vf, pf[ks], o_acc[dt], 0, 0, 0);
                }
            }
        }

        // ---- epilogue: normalize, write bf16 (B,S,H*64) ----
        const float inv = 1.0f / l_run;
        ushort_t* orow = Og + ((size_t)(b_out * S_ + qrow)) * DM_ + h_out * HD_;
#pragma unroll
        for (int dt = 0; dt < 2; ++dt)
#pragma unroll
            for (int c = 0; c < 4; ++c) {
                uint2 pk;
                pk.x = (unsigned)f2bf(o_acc[dt][c * 4 + 0] * inv) |
                       ((unsigned)f2bf(o_acc[dt][c * 4 + 1] * inv) << 16);
                pk.y = (unsigned)f2bf(o_acc[dt][c * 4 + 2] * inv) |
                       ((unsigned)f2bf(o_acc[dt][c * 4 + 3] * inv) << 16);
                *(uint2*)(orow + dt * 32 + 8 * c + 4 * h) = pk;
            }
    }
}

// ---------------------------------------------------------------------------
extern "C" void kernel_launch(void* const* d_in, const int* in_sizes, int n_in,
                              void* d_out, int out_size, void* d_ws, size_t ws_size,
                              hipStream_t stream)
{
    const float* x  = (const float*)d_in[0];
    const float* cf = (const float*)d_in[1];
    const float* sf = (const float*)d_in[2];
    // d_in[3] = causal_mask: computed analytically, never read
    const float* wq = (const float*)d_in[4];
    const float* wk = (const float*)d_in[5];
    const float* wv = (const float*)d_in[6];
    const float* wo = (const float*)d_in[7];
    float* out = (float*)d_out;

    const size_t NELEM = (size_t)B_ * S_ * DM_;   // 8388608
    const size_t WELEM = (size_t)DM_ * DM_;       // 1048576
    ushort_t* xb  = (ushort_t*)d_ws;
    ushort_t* qb  = xb + NELEM;
    ushort_t* kb  = qb + NELEM;
    ushort_t* vb  = kb + NELEM;                   // V^T (B,H,64,S)
    ushort_t* ao  = vb + NELEM;
    ushort_t* wqb = ao + NELEM;
    ushort_t* wkb = wqb + WELEM;
    ushort_t* wvb = wkb + WELEM;
    ushort_t* wob = wvb + WELEM;

    cvt_all_kernel<<<dim3(8192 + 4 * 1024), 256, 0, stream>>>(
        x, wq, wk, wv, wo, xb, wqb, wkb, wvb, wob);

    const int M = B_ * S_;
    gemm_bt_kernel<<<dim3(M / 128, DM_ / 128, 3), 256, 0, stream>>>(
        xb, wqb, wkb, wvb, qb, kb, vb, M, DM_, DM_, 0);
    rope_kernel<<<dim3((B_ * NH_ * S_ * 32) / 256), 256, 0, stream>>>(qb, kb, cf, sf);
    attn_kernel<<<dim3(8, B_ * NH_), 256, 0, stream>>>(qb, kb, vb, ao);
    gemm_bt_kernel<<<dim3(M / 128, DM_ / 128, 1), 256, 0, stream>>>(
        ao, wob, wob, wob, out, out, out, M, DM_, DM_, 1);
}